// Round 1
// baseline (471.713 us; speedup 1.0000x reference)
//
#include <hip/hip_runtime.h>
#include <hip/hip_bf16.h>
#include <hip/hip_cooperative_groups.h>

namespace cg = cooperative_groups;

typedef __attribute__((ext_vector_type(8))) unsigned short u16x8;
typedef __attribute__((ext_vector_type(4))) unsigned short u16x4;
typedef __attribute__((ext_vector_type(8))) short short8;
typedef __attribute__((ext_vector_type(4))) float floatx4;

#define BS 64
#define CIN 256
#define II 1024
#define OO 320
#define JJ 10
#define DD 32

__device__ __forceinline__ float b2f(unsigned short u) {
    union { unsigned int i; float f; } x; x.i = ((unsigned int)u) << 16; return x.f;
}
__device__ __forceinline__ unsigned short f2b(float f) {
    union { float f; unsigned int i; } x; x.f = f;
    unsigned int r = x.i + 0x7fffu + ((x.i >> 16) & 1u);
    return (unsigned short)(r >> 16);
}

// multi-output butterfly: 32 per-lane partials p[d] -> sum over 64 lanes.
// After: lane l (l<32) holds total for d = l&31.
__device__ __forceinline__ float butterfly32(const float* p, int l) {
    float q16[16];
#pragma unroll
    for (int d = 0; d < 16; ++d) {
        float keep = (l & 1) ? p[2 * d + 1] : p[2 * d];
        float send = (l & 1) ? p[2 * d] : p[2 * d + 1];
        q16[d] = keep + __shfl_xor(send, 1);
    }
    float q8[8];
#pragma unroll
    for (int d = 0; d < 8; ++d) {
        float keep = (l & 2) ? q16[2 * d + 1] : q16[2 * d];
        float send = (l & 2) ? q16[2 * d] : q16[2 * d + 1];
        q8[d] = keep + __shfl_xor(send, 2);
    }
    float q4[4];
#pragma unroll
    for (int d = 0; d < 4; ++d) {
        float keep = (l & 4) ? q8[2 * d + 1] : q8[2 * d];
        float send = (l & 4) ? q8[2 * d] : q8[2 * d + 1];
        q4[d] = keep + __shfl_xor(send, 4);
    }
    float q2[2];
#pragma unroll
    for (int d = 0; d < 2; ++d) {
        float keep = (l & 8) ? q4[2 * d + 1] : q4[2 * d];
        float send = (l & 8) ? q4[2 * d] : q4[2 * d + 1];
        q2[d] = keep + __shfl_xor(send, 8);
    }
    float keep = (l & 16) ? q2[1] : q2[0];
    float send = (l & 16) ? q2[0] : q2[1];
    float q1 = keep + __shfl_xor(send, 16);
    q1 += __shfl_xor(q1, 32);
    return q1;
}

// 16-value multi-output butterfly over the 16-lane lm group (strides 1,2,4,8).
// After: lane with lm = l&15 holds sum over the 16 lm-lanes of p[lm].
__device__ __forceinline__ float butterfly16(const float* p, int l) {
    float q8[8];
#pragma unroll
    for (int d = 0; d < 8; ++d) {
        float keep = (l & 1) ? p[2 * d + 1] : p[2 * d];
        float send = (l & 1) ? p[2 * d] : p[2 * d + 1];
        q8[d] = keep + __shfl_xor(send, 1);
    }
    float q4[4];
#pragma unroll
    for (int d = 0; d < 4; ++d) {
        float keep = (l & 2) ? q8[2 * d + 1] : q8[2 * d];
        float send = (l & 2) ? q8[2 * d] : q8[2 * d + 1];
        q4[d] = keep + __shfl_xor(send, 2);
    }
    float q2[2];
#pragma unroll
    for (int d = 0; d < 2; ++d) {
        float keep = (l & 4) ? q4[2 * d + 1] : q4[2 * d];
        float send = (l & 4) ? q4[2 * d] : q4[2 * d + 1];
        q2[d] = keep + __shfl_xor(send, 4);
    }
    float keep = (l & 8) ? q2[1] : q2[0];
    float send = (l & 8) ? q2[0] : q2[1];
    return keep + __shfl_xor(send, 8);
}

// ---------- prep: W f32 [320][256] -> 64-o-chunk frag-linear bf16 Wl ----------
__global__ __launch_bounds__(256) void k_prepW(const float* __restrict__ W,
                                               unsigned short* __restrict__ Wl) {
    int gid = blockIdx.x * 256 + threadIdx.x;   // 40 blocks -> 10240
    int lm = gid & 15;
    int quad = (gid >> 4) & 3;
    int mtl = (gid >> 6) & 3;
    int ks = (gid >> 8) & 7;
    int oc = gid >> 11;
    const float* src = W + (size_t)(oc * 64 + mtl * 16 + lm) * CIN + ks * 32 + quad * 8;
    float4 v0 = *(const float4*)src;
    float4 v1 = *(const float4*)(src + 4);
    u16x8 u;
    u[0] = f2b(v0.x); u[1] = f2b(v0.y); u[2] = f2b(v0.z); u[3] = f2b(v0.w);
    u[4] = f2b(v1.x); u[5] = f2b(v1.y); u[6] = f2b(v1.z); u[7] = f2b(v1.w);
    *(u16x8*)(Wl + (size_t)gid * 8) = u;
}

// ============================================================================
//                 FUSED COOPERATIVE MEGA-KERNEL (primary path)
// pred never touches HBM: each thread holds its 80 pred values as 40 packed
// bf16x2 VGPRs.  3 grid syncs at the cross-block (per-batch over 8 ic chunks)
// reduction points.  b-logits live in registers across routing passes.
// ============================================================================

// one routing pass: reduce partials -> s -> squash v -> delta (quad shuffle)
// -> b update -> thread-local softmax over j -> c*pred partial sums
// (lm butterfly + LDS atomics) -> write per-block partial [ic][b][320].
__device__ __forceinline__ void route_pass(
        const float* __restrict__ srcpart, float scale, bool first,
        const unsigned* pk, float* b_reg, float* __restrict__ dstpart,
        float* sacc, float* v_lds, float* cf,
        int ic, int b, int t, int l, int lm, int quad) {
    if (t < OO) {
        float s = 0.f;
#pragma unroll
        for (int sl = 0; sl < 8; ++sl) s += srcpart[((size_t)sl * BS + b) * OO + t];
        sacc[t] = scale * s;
    }
    __syncthreads();
    if (t < JJ) {
        float n2 = 0.f;
#pragma unroll
        for (int d = 0; d < DD; ++d) { float v = sacc[t * DD + d]; n2 += v * v; }
        cf[t] = sqrtf(n2) / (1.0f + n2);
    }
    __syncthreads();
    if (t < OO) { v_lds[t] = sacc[t] * cf[t >> 5]; sacc[t] = 0.f; }
    __syncthreads();

    // delta[i][j] = sum_d v[j][d]*pred[i][j][d]; thread holds 8 d per j (by quad)
    float dj[JJ];
#pragma unroll
    for (int j = 0; j < JJ; ++j) dj[j] = 0.f;
#pragma unroll
    for (int m = 0; m < 20; ++m) {       // o = m*16 + quad*4 + r
        float4 vv = *(const float4*)&v_lds[m * 16 + quad * 4];
        unsigned a0 = pk[2 * m], a1 = pk[2 * m + 1];
        dj[m >> 1] += b2f((unsigned short)(a0 & 0xffffu)) * vv.x
                    + b2f((unsigned short)(a0 >> 16)) * vv.y
                    + b2f((unsigned short)(a1 & 0xffffu)) * vv.z
                    + b2f((unsigned short)(a1 >> 16)) * vv.w;
    }
#pragma unroll
    for (int j = 0; j < JJ; ++j) {       // complete dot over quads
        float d = dj[j];
        d += __shfl_xor(d, 16);
        d += __shfl_xor(d, 32);
        b_reg[j] = first ? d : (b_reg[j] + d);
    }
    // thread-local softmax over j (thread owns all 10 j of its i)
    float mx = b_reg[0];
#pragma unroll
    for (int j = 1; j < JJ; ++j) mx = fmaxf(mx, b_reg[j]);
    float cj[JJ], Z = 0.f;
#pragma unroll
    for (int j = 0; j < JJ; ++j) { cj[j] = __expf(b_reg[j] - mx); Z += cj[j]; }
    float inv = 1.0f / Z;
    // psum[j][d] partial over block's 128 i: 5 groups of 16 -> lm butterfly
#pragma unroll
    for (int g = 0; g < 5; ++g) {
        float v16[16];
#pragma unroll
        for (int mm = 0; mm < 4; ++mm) {
            int m = 4 * g + mm;
            unsigned a0 = pk[2 * m], a1 = pk[2 * m + 1];
            float c = cj[m >> 1] * inv;
            v16[4 * mm + 0] = c * b2f((unsigned short)(a0 & 0xffffu));
            v16[4 * mm + 1] = c * b2f((unsigned short)(a0 >> 16));
            v16[4 * mm + 2] = c * b2f((unsigned short)(a1 & 0xffffu));
            v16[4 * mm + 3] = c * b2f((unsigned short)(a1 >> 16));
        }
        float q = butterfly16(v16, l);
        atomicAdd(&sacc[g * 64 + (lm >> 2) * 16 + quad * 4 + (lm & 3)], q);
    }
    __syncthreads();
    if (t < OO) dstpart[((size_t)ic * BS + b) * OO + t] = sacc[t];
}

__global__ __launch_bounds__(512, 4) void k_mega(
        const float* __restrict__ x, const unsigned short* __restrict__ Wl,
        const float* __restrict__ Wb, float* __restrict__ s1part,
        float* __restrict__ psum1, float* __restrict__ psum2,
        float* __restrict__ out) {
    __shared__ unsigned short buf[2][16896];        // 67,584 B
    __shared__ float Wb_lds[OO];
    __shared__ float sacc[OO];
    __shared__ __align__(16) float v_lds[OO];
    __shared__ float cf[16];

    cg::grid_group gg = cg::this_grid();

    const int ic = blockIdx.x, b = blockIdx.y;
    const int t = threadIdx.x, w = t >> 6, l = t & 63;
    const int lm = l & 15, quad = l >> 4;
    const int i0 = ic * 128;

    if (t < OO) { Wb_lds[t] = Wb[t]; sacc[t] = 0.f; }

    // W chunk 0 -> buf[1] (covered by first staging barrier)
    {
        const u16x8* src = (const u16x8*)Wl;
        u16x8* dst = (u16x8*)buf[1];
        dst[t] = src[t];
        dst[t + 512] = src[t + 512];
        dst[t + 1024] = src[t + 1024];
        dst[t + 1536] = src[t + 1536];
    }

    // ---- stage x in two K-halves through buf[0]; build B-frags ----
    short8 bfrag[8];
    const int crow = t >> 5, f4 = t & 31;
#pragma unroll
    for (int kc = 0; kc < 2; ++kc) {
        float4 fr[8];
#pragma unroll
        for (int p = 0; p < 8; ++p) {
            int c = kc * 128 + p * 16 + crow;
            fr[p] = *(const float4*)(x + ((size_t)b * CIN + c) * II + i0 + 4 * f4);
        }
#pragma unroll
        for (int p = 0; p < 8; ++p) {
            int cl = p * 16 + crow;
            u16x4 u;
            u[0] = f2b(fr[p].x); u[1] = f2b(fr[p].y); u[2] = f2b(fr[p].z); u[3] = f2b(fr[p].w);
            *(u16x4*)&buf[0][cl * 132 + 4 * f4] = u;
        }
        __syncthreads();
#pragma unroll
        for (int k2 = 0; k2 < 4; ++k2) {
            short8 f;
#pragma unroll
            for (int j = 0; j < 8; ++j)
                f[j] = (short)buf[0][(k2 * 32 + quad * 8 + j) * 132 + w * 16 + lm];
            bfrag[kc * 4 + k2] = f;
        }
        __syncthreads();
    }

    // ---- GEMM: o-chunk loop fully unrolled so pred pack regs stay static ----
    // Thread (w,quad,lm) owns i = i0 + w*16 + lm; pred value at
    // o = oc*64 + mtl*16 + quad*4 + r  packed into pk[(oc*4+mtl)*2 + (r>>1)].
    unsigned pk[40];
#pragma unroll
    for (int oc = 0; oc < 5; ++oc) {
        if (oc < 4) {
            const u16x8* src = (const u16x8*)Wl + (size_t)(oc + 1) * 2048;
            u16x8* dst = (u16x8*)buf[oc & 1];
            dst[t] = src[t];
            dst[t + 512] = src[t + 512];
            dst[t + 1024] = src[t + 1024];
            dst[t + 1536] = src[t + 1536];
        }
        const unsigned short* ab = buf[(oc + 1) & 1];
        floatx4 acc[4] = {};
#pragma unroll
        for (int ks = 0; ks < 8; ++ks)
#pragma unroll
            for (int mtl = 0; mtl < 4; ++mtl) {
                short8 af = *(const short8*)(ab + (size_t)(((ks * 4 + mtl) * 4 + quad) * 16 + lm) * 8);
                acc[mtl] = __builtin_amdgcn_mfma_f32_16x16x32_bf16(af, bfrag[ks], acc[mtl], 0, 0, 0);
            }
        // bias + pack to registers (bf16, same rounding as old HBM pred)
        float av[16];
#pragma unroll
        for (int mtl = 0; mtl < 4; ++mtl) {
            int ob = oc * 64 + mtl * 16 + quad * 4;
#pragma unroll
            for (int r = 0; r < 4; ++r) av[mtl * 4 + r] = acc[mtl][r] + Wb_lds[ob + r];
            pk[oc * 8 + mtl * 2 + 0] =
                (unsigned)f2b(av[mtl * 4 + 0]) | ((unsigned)f2b(av[mtl * 4 + 1]) << 16);
            pk[oc * 8 + mtl * 2 + 1] =
                (unsigned)f2b(av[mtl * 4 + 2]) | ((unsigned)f2b(av[mtl * 4 + 3]) << 16);
        }
        // s1 partial: sum biased f32 pred over this wave's 16 i, accumulate in LDS
        float q = butterfly16(av, l);
        atomicAdd(&sacc[oc * 64 + (lm >> 2) * 16 + quad * 4 + (lm & 3)], q);
        __syncthreads();
    }

    // per-block s1 partial (sum over 128 i, bias included -> 1024*Wb overall)
    if (t < OO) s1part[((size_t)ic * BS + b) * OO + t] = sacc[t];
    __threadfence();
    gg.sync();

    // ---- routing pass 1 (c uniform handled by 0.1*s1) ----
    float b_reg[JJ];
    route_pass(s1part, 0.1f, true, pk, b_reg, psum1, sacc, v_lds, cf, ic, b, t, l, lm, quad);
    __threadfence();
    gg.sync();

    // ---- routing pass 2 ----
    route_pass(psum1, 1.0f, false, pk, b_reg, psum2, sacc, v_lds, cf, ic, b, t, l, lm, quad);
    __threadfence();
    gg.sync();

    // ---- final squash + output (one block per batch) ----
    if (ic == 0) {
        if (t < OO) {
            float s = 0.f;
#pragma unroll
            for (int sl = 0; sl < 8; ++sl) s += psum2[((size_t)sl * BS + b) * OO + t];
            sacc[t] = s;
        }
        __syncthreads();
        if (t < JJ) {
            float n2 = 0.f;
#pragma unroll
            for (int d = 0; d < DD; ++d) { float v = sacc[t * DD + d]; n2 += v * v; }
            cf[t] = sqrtf(n2) / (1.0f + n2);
        }
        __syncthreads();
        if (t < OO) out[b * OO + t] = sacc[t] * cf[t >> 5];
    }
}

// ============================================================================
//            FALLBACK: verified 6-kernel pipeline (unchanged)
// ============================================================================

__global__ __launch_bounds__(512) void k_gemm8(const float* __restrict__ x,
                                               const unsigned short* __restrict__ Wl,
                                               const float* __restrict__ Wb,
                                               unsigned short* __restrict__ pred,
                                               float* __restrict__ psumC) {
    __shared__ unsigned short buf[2][16896];
    __shared__ float Wb_lds[OO];

    const int ic = blockIdx.x, b = blockIdx.y;
    const int t = threadIdx.x, w = t >> 6, l = t & 63;
    const int lm = l & 15, quad = l >> 4;
    const int i0 = ic * 128;

    if (t < OO) Wb_lds[t] = Wb[t];

    {
        const u16x8* src = (const u16x8*)Wl;
        u16x8* dst = (u16x8*)buf[1];
        dst[t] = src[t];
        dst[t + 512] = src[t + 512];
        dst[t + 1024] = src[t + 1024];
        dst[t + 1536] = src[t + 1536];
    }

    short8 bfrag[8];
    float csum[2];
    const int crow = t >> 5, f4 = t & 31;
    const int cs_c = t >> 2, cs_seg = t & 3;
#pragma unroll
    for (int kc = 0; kc < 2; ++kc) {
        float4 fr[8];
#pragma unroll
        for (int p = 0; p < 8; ++p) {
            int c = kc * 128 + p * 16 + crow;
            fr[p] = *(const float4*)(x + ((size_t)b * CIN + c) * II + i0 + 4 * f4);
        }
#pragma unroll
        for (int p = 0; p < 8; ++p) {
            int cl = p * 16 + crow;
            u16x4 u;
            u[0] = f2b(fr[p].x); u[1] = f2b(fr[p].y); u[2] = f2b(fr[p].z); u[3] = f2b(fr[p].w);
            *(u16x4*)&buf[0][cl * 132 + 4 * f4] = u;
        }
        __syncthreads();
#pragma unroll
        for (int k2 = 0; k2 < 4; ++k2) {
            short8 f;
#pragma unroll
            for (int j = 0; j < 8; ++j)
                f[j] = (short)buf[0][(k2 * 32 + quad * 8 + j) * 132 + w * 16 + lm];
            bfrag[kc * 4 + k2] = f;
        }
        {
            float cs = 0.f;
#pragma unroll
            for (int q = 0; q < 8; ++q) {
                u16x4 u = *(const u16x4*)&buf[0][cs_c * 132 + cs_seg * 32 + q * 4];
                cs += b2f(u[0]) + b2f(u[1]) + b2f(u[2]) + b2f(u[3]);
            }
            cs += __shfl_xor(cs, 1);
            cs += __shfl_xor(cs, 2);
            csum[kc] = cs;
        }
        __syncthreads();
    }
    if (cs_seg == 0) {
        size_t cbase = ((size_t)ic * BS + b) * CIN;
        psumC[cbase + cs_c] = csum[0];
        psumC[cbase + 128 + cs_c] = csum[1];
    }

    const size_t predrow = ((size_t)b * II + i0 + w * 16 + lm) * OO;
#pragma unroll 1
    for (int oc = 0; oc < 5; ++oc) {
        if (oc < 4) {
            const u16x8* src = (const u16x8*)Wl + (size_t)(oc + 1) * 2048;
            u16x8* dst = (u16x8*)buf[oc & 1];
            dst[t] = src[t];
            dst[t + 512] = src[t + 512];
            dst[t + 1024] = src[t + 1024];
            dst[t + 1536] = src[t + 1536];
        }
        const unsigned short* ab = buf[(oc + 1) & 1];
        floatx4 acc[4] = {};
#pragma unroll
        for (int ks = 0; ks < 8; ++ks)
#pragma unroll
            for (int mtl = 0; mtl < 4; ++mtl) {
                short8 af = *(const short8*)(ab + (size_t)(((ks * 4 + mtl) * 4 + quad) * 16 + lm) * 8);
                acc[mtl] = __builtin_amdgcn_mfma_f32_16x16x32_bf16(af, bfrag[ks], acc[mtl], 0, 0, 0);
            }
#pragma unroll
        for (int mtl = 0; mtl < 4; ++mtl) {
            int ob = oc * 64 + mtl * 16 + quad * 4;
            u16x4 sv;
#pragma unroll
            for (int r = 0; r < 4; ++r) sv[r] = f2b(acc[mtl][r] + Wb_lds[ob + r]);
            *(u16x4*)(pred + predrow + ob) = sv;
        }
        __syncthreads();
    }
}

__global__ __launch_bounds__(320) void k_gemv(const float* __restrict__ psumC,
                                              const float* __restrict__ W,
                                              const float* __restrict__ Wb,
                                              float* __restrict__ s1) {
    __shared__ float y_lds[CIN];
    const int b = blockIdx.x, t = threadIdx.x;
    if (t < CIN) {
        float s = 0.f;
#pragma unroll
        for (int sl = 0; sl < 8; ++sl) s += psumC[((size_t)sl * BS + b) * CIN + t];
        y_lds[t] = s;
    }
    __syncthreads();
    const float* wr = W + (size_t)t * CIN;
    float acc = 0.f;
#pragma unroll 4
    for (int c = 0; c < CIN; c += 4) {
        float4 wv = *(const float4*)(wr + c);
        acc += wv.x * y_lds[c] + wv.y * y_lds[c + 1] + wv.z * y_lds[c + 2] + wv.w * y_lds[c + 3];
    }
    s1[(size_t)b * OO + t] = 0.1f * (acc + 1024.0f * Wb[t]);
}

__global__ __launch_bounds__(640) void k_route1(const float* __restrict__ s1,
                                                const unsigned short* __restrict__ pred,
                                                float* __restrict__ blogG,
                                                float* __restrict__ psum1) {
    __shared__ float s_lds[OO];
    __shared__ float v_lds[OO];
    __shared__ float cf[JJ];
    __shared__ float dbuf[JJ][128];

    const int ic = blockIdx.x, b = blockIdx.y;
    const int t = threadIdx.x, w = t >> 6, l = t & 63;

    u16x8 va[4], vb[4];
    {
        const unsigned short* p0 = pred + ((size_t)b * II + ic * 128 + 2 * l) * OO + w * DD;
#pragma unroll
        for (int q = 0; q < 4; ++q) {
            va[q] = *(const u16x8*)(p0 + q * 8);
            vb[q] = *(const u16x8*)(p0 + OO + q * 8);
        }
    }

    if (t < OO) s_lds[t] = s1[(size_t)b * OO + t];
    __syncthreads();
    if (t < JJ) {
        float n2 = 0.f;
#pragma unroll
        for (int d = 0; d < DD; ++d) { float v = s_lds[t * DD + d]; n2 += v * v; }
        cf[t] = sqrtf(n2) / (1.0f + n2);
    }
    __syncthreads();
    if (t < OO) v_lds[t] = s_lds[t] * cf[t >> 5];
    __syncthreads();

    float d0 = 0.f, d1 = 0.f;
#pragma unroll
    for (int q = 0; q < 4; ++q)
#pragma unroll
        for (int e = 0; e < 8; ++e) {
            float vv = v_lds[w * DD + q * 8 + e];
            d0 += vv * b2f(va[q][e]);
            d1 += vv * b2f(vb[q][e]);
        }
    *(float2*)(blogG + ((size_t)b * JJ + w) * II + ic * 128 + 2 * l) = make_float2(d0, d1);
    dbuf[w][2 * l] = d0; dbuf[w][2 * l + 1] = d1;
    __syncthreads();

    if (t < 128) {
        float lg[JJ];
#pragma unroll
        for (int j = 0; j < JJ; ++j) lg[j] = dbuf[j][t];
        float m = lg[0];
#pragma unroll
        for (int j = 1; j < JJ; ++j) m = fmaxf(m, lg[j]);
        float Z = 0.f, c[JJ];
#pragma unroll
        for (int j = 0; j < JJ; ++j) { c[j] = __expf(lg[j] - m); Z += c[j]; }
        float inv = 1.0f / Z;
#pragma unroll
        for (int j = 0; j < JJ; ++j) dbuf[j][t] = c[j] * inv;
    }
    __syncthreads();

    float c0 = dbuf[w][2 * l], c1 = dbuf[w][2 * l + 1];
    float p[DD];
#pragma unroll
    for (int q = 0; q < 4; ++q)
#pragma unroll
        for (int e = 0; e < 8; ++e)
            p[q * 8 + e] = c0 * b2f(va[q][e]) + c1 * b2f(vb[q][e]);
    float s = butterfly32(p, l);
    if (l < 32) psum1[((size_t)ic * BS + b) * OO + w * DD + l] = s;
}

__global__ __launch_bounds__(640) void k_route2(const float* __restrict__ psum1,
                                                const unsigned short* __restrict__ pred,
                                                const float* __restrict__ blogG,
                                                float* __restrict__ psum2) {
    __shared__ float s_lds[OO];
    __shared__ float v_lds[OO];
    __shared__ float cf[JJ];
    __shared__ float dbuf[JJ][128];

    const int ic = blockIdx.x, b = blockIdx.y;
    const int t = threadIdx.x, w = t >> 6, l = t & 63;

    u16x8 va[4], vb[4];
    {
        const unsigned short* p0 = pred + ((size_t)b * II + ic * 128 + 2 * l) * OO + w * DD;
#pragma unroll
        for (int q = 0; q < 4; ++q) {
            va[q] = *(const u16x8*)(p0 + q * 8);
            vb[q] = *(const u16x8*)(p0 + OO + q * 8);
        }
    }

    if (t < OO) {
        float s = 0.f;
#pragma unroll
        for (int sl = 0; sl < 8; ++sl) s += psum1[((size_t)sl * BS + b) * OO + t];
        s_lds[t] = s;
    }
    __syncthreads();
    if (t < JJ) {
        float n2 = 0.f;
#pragma unroll
        for (int d = 0; d < DD; ++d) { float v = s_lds[t * DD + d]; n2 += v * v; }
        cf[t] = sqrtf(n2) / (1.0f + n2);
    }
    __syncthreads();
    if (t < OO) v_lds[t] = s_lds[t] * cf[t >> 5];
    __syncthreads();

    float d0 = 0.f, d1 = 0.f;
#pragma unroll
    for (int q = 0; q < 4; ++q)
#pragma unroll
        for (int e = 0; e < 8; ++e) {
            float vv = v_lds[w * DD + q * 8 + e];
            d0 += vv * b2f(va[q][e]);
            d1 += vv * b2f(vb[q][e]);
        }
    float2 bl = *(const float2*)(blogG + ((size_t)b * JJ + w) * II + ic * 128 + 2 * l);
    dbuf[w][2 * l] = bl.x + d0; dbuf[w][2 * l + 1] = bl.y + d1;
    __syncthreads();

    if (t < 128) {
        float lg[JJ];
#pragma unroll
        for (int j = 0; j < JJ; ++j) lg[j] = dbuf[j][t];
        float m = lg[0];
#pragma unroll
        for (int j = 1; j < JJ; ++j) m = fmaxf(m, lg[j]);
        float Z = 0.f, c[JJ];
#pragma unroll
        for (int j = 0; j < JJ; ++j) { c[j] = __expf(lg[j] - m); Z += c[j]; }
        float inv = 1.0f / Z;
#pragma unroll
        for (int j = 0; j < JJ; ++j) dbuf[j][t] = c[j] * inv;
    }
    __syncthreads();

    float c0 = dbuf[w][2 * l], c1 = dbuf[w][2 * l + 1];
    float p[DD];
#pragma unroll
    for (int q = 0; q < 4; ++q)
#pragma unroll
        for (int e = 0; e < 8; ++e)
            p[q * 8 + e] = c0 * b2f(va[q][e]) + c1 * b2f(vb[q][e]);
    float s = butterfly32(p, l);
    if (l < 32) psum2[((size_t)ic * BS + b) * OO + w * DD + l] = s;
}

__global__ __launch_bounds__(320) void k_final2(const float* __restrict__ psum2,
                                                float* __restrict__ out) {
    __shared__ float s_lds[OO];
    __shared__ float cf[JJ];
    int b = blockIdx.x, t = threadIdx.x;
    float s = 0.f;
#pragma unroll
    for (int sl = 0; sl < 8; ++sl) s += psum2[((size_t)sl * BS + b) * OO + t];
    s_lds[t] = s;
    __syncthreads();
    if (t < JJ) {
        float n2 = 0.f;
#pragma unroll
        for (int d = 0; d < DD; ++d) { float v = s_lds[t * DD + d]; n2 += v * v; }
        cf[t] = sqrtf(n2) / (1.0f + n2);
    }
    __syncthreads();
    out[b * OO + t] = s_lds[t] * cf[t >> 5];
}

extern "C" void kernel_launch(void* const* d_in, const int* in_sizes, int n_in,
                              void* d_out, int out_size, void* d_ws, size_t ws_size,
                              hipStream_t stream) {
    const float* x  = (const float*)d_in[0];  // [64][256][1024] f32
    const float* W  = (const float*)d_in[1];  // [320][256] f32
    const float* Wb = (const float*)d_in[2];  // [320] f32

    char* ws = (char*)d_ws;
    unsigned short* pred = (unsigned short*)ws;              // 41,943,040 B  (fallback only)
    unsigned short* Wl   = (unsigned short*)(ws + 41943040); // 163,840 B
    float* psumC = (float*)(ws + 42106880);                  // 524,288 B (fallback only)
    float* s1    = (float*)(ws + 42631168);                  // 81,920 B  (fallback only)
    float* psum1 = (float*)(ws + 42713088);                  // 655,360 B
    float* psum2 = (float*)(ws + 43368448);                  // 655,360 B
    float* blogG = (float*)(ws + 44023808);                  // 2,621,440 B (fallback only)
    float* s1part = (float*)(ws + 46645248);                 // 655,360 B (mega only)

    k_prepW<<<40, 256, 0, stream>>>(W, Wl);

    // primary: single cooperative fused kernel (pred stays in VGPRs)
    {
        const float* a0 = x;
        const unsigned short* a1 = Wl;
        const float* a2 = Wb;
        float* a3 = s1part;
        float* a4 = psum1;
        float* a5 = psum2;
        float* a6 = (float*)d_out;
        void* kargs[] = {&a0, &a1, &a2, &a3, &a4, &a5, &a6};
        hipError_t e = hipLaunchCooperativeKernel(k_mega, dim3(8, BS), dim3(512, 1, 1),
                                                  kargs, 0, stream);
        if (e == hipSuccess) return;
    }

    // fallback: verified 6-kernel pipeline
    k_gemm8<<<dim3(8, BS), 512, 0, stream>>>(x, Wl, Wb, pred, psumC);
    k_gemv<<<BS, 320, 0, stream>>>(psumC, W, Wb, s1);
    k_route1<<<dim3(8, BS), 640, 0, stream>>>(s1, pred, blogG, psum1);
    k_route2<<<dim3(8, BS), 640, 0, stream>>>(psum1, pred, blogG, psum2);
    k_final2<<<BS, 320, 0, stream>>>(psum2, (float*)d_out);
}

// Round 2
// 315.790 us; speedup vs baseline: 1.4938x; 1.4938x over previous
//
#include <hip/hip_runtime.h>
#include <hip/hip_bf16.h>
#include <hip/hip_cooperative_groups.h>

namespace cg = cooperative_groups;

typedef __attribute__((ext_vector_type(8))) unsigned short u16x8;
typedef __attribute__((ext_vector_type(4))) unsigned short u16x4;
typedef __attribute__((ext_vector_type(8))) short short8;
typedef __attribute__((ext_vector_type(4))) float floatx4;

#define BS 64
#define CIN 256
#define II 1024
#define OO 320
#define JJ 10
#define DD 32

__device__ __forceinline__ float b2f(unsigned short u) {
    union { unsigned int i; float f; } x; x.i = ((unsigned int)u) << 16; return x.f;
}
__device__ __forceinline__ unsigned short f2b(float f) {
    union { float f; unsigned int i; } x; x.f = f;
    unsigned int r = x.i + 0x7fffu + ((x.i >> 16) & 1u);
    return (unsigned short)(r >> 16);
}

// multi-output butterfly: 32 per-lane partials p[d] -> sum over 64 lanes.
// After: lane l (l<32) holds total for d = l&31.  (fallback kernels)
__device__ __forceinline__ float butterfly32(const float* p, int l) {
    float q16[16];
#pragma unroll
    for (int d = 0; d < 16; ++d) {
        float keep = (l & 1) ? p[2 * d + 1] : p[2 * d];
        float send = (l & 1) ? p[2 * d] : p[2 * d + 1];
        q16[d] = keep + __shfl_xor(send, 1);
    }
    float q8[8];
#pragma unroll
    for (int d = 0; d < 8; ++d) {
        float keep = (l & 2) ? q16[2 * d + 1] : q16[2 * d];
        float send = (l & 2) ? q16[2 * d] : q16[2 * d + 1];
        q8[d] = keep + __shfl_xor(send, 2);
    }
    float q4[4];
#pragma unroll
    for (int d = 0; d < 4; ++d) {
        float keep = (l & 4) ? q8[2 * d + 1] : q8[2 * d];
        float send = (l & 4) ? q8[2 * d] : q8[2 * d + 1];
        q4[d] = keep + __shfl_xor(send, 4);
    }
    float q2[2];
#pragma unroll
    for (int d = 0; d < 2; ++d) {
        float keep = (l & 8) ? q4[2 * d + 1] : q4[2 * d];
        float send = (l & 8) ? q4[2 * d] : q4[2 * d + 1];
        q2[d] = keep + __shfl_xor(send, 8);
    }
    float keep = (l & 16) ? q2[1] : q2[0];
    float send = (l & 16) ? q2[0] : q2[1];
    float q1 = keep + __shfl_xor(send, 16);
    q1 += __shfl_xor(q1, 32);
    return q1;
}

// 16-value multi-output butterfly over the 16-lane lm group (strides 1,2,4,8).
// After: lane with lm = l&15 holds sum over the 16 lm-lanes of p[lm].
__device__ __forceinline__ float butterfly16(const float* p, int l) {
    float q8[8];
#pragma unroll
    for (int d = 0; d < 8; ++d) {
        float keep = (l & 1) ? p[2 * d + 1] : p[2 * d];
        float send = (l & 1) ? p[2 * d] : p[2 * d + 1];
        q8[d] = keep + __shfl_xor(send, 1);
    }
    float q4[4];
#pragma unroll
    for (int d = 0; d < 4; ++d) {
        float keep = (l & 2) ? q8[2 * d + 1] : q8[2 * d];
        float send = (l & 2) ? q8[2 * d] : q8[2 * d + 1];
        q4[d] = keep + __shfl_xor(send, 2);
    }
    float q2[2];
#pragma unroll
    for (int d = 0; d < 2; ++d) {
        float keep = (l & 4) ? q4[2 * d + 1] : q4[2 * d];
        float send = (l & 4) ? q4[2 * d] : q4[2 * d + 1];
        q2[d] = keep + __shfl_xor(send, 4);
    }
    float keep = (l & 8) ? q2[1] : q2[0];
    float send = (l & 8) ? q2[0] : q2[1];
    return keep + __shfl_xor(send, 8);
}

// ---------- prep: W f32 [320][256] -> 64-o-chunk frag-linear bf16 Wl ----------
__global__ __launch_bounds__(256) void k_prepW(const float* __restrict__ W,
                                               unsigned short* __restrict__ Wl) {
    int gid = blockIdx.x * 256 + threadIdx.x;   // 40 blocks -> 10240
    int lm = gid & 15;
    int quad = (gid >> 4) & 3;
    int mtl = (gid >> 6) & 3;
    int ks = (gid >> 8) & 7;
    int oc = gid >> 11;
    const float* src = W + (size_t)(oc * 64 + mtl * 16 + lm) * CIN + ks * 32 + quad * 8;
    float4 v0 = *(const float4*)src;
    float4 v1 = *(const float4*)(src + 4);
    u16x8 u;
    u[0] = f2b(v0.x); u[1] = f2b(v0.y); u[2] = f2b(v0.z); u[3] = f2b(v0.w);
    u[4] = f2b(v1.x); u[5] = f2b(v1.y); u[6] = f2b(v1.z); u[7] = f2b(v1.w);
    *(u16x8*)(Wl + (size_t)gid * 8) = u;
}

// ============================================================================
//        FUSED COOPERATIVE MEGA-KERNEL v2  (256 blocks = 1/CU, 256-reg budget)
// Each block covers 256 i (two sequential 128-i sub-tiles).  pred never
// touches HBM: per thread 2x40 packed bf16x2 VGPRs.  b-logits in registers.
// ============================================================================

// one 128-i sub-tile: stage x, MFMA GEMM over 5 o-chunks, bias+pack pred to
// pk, accumulate per-block colsum-of-pred into sacc (for s1).
__device__ __forceinline__ void gemm_subtile(
        const float* __restrict__ x, const unsigned short* __restrict__ Wl,
        unsigned short (&buf)[2][16896], const float* Wb_lds, float* sacc,
        int b, int i0, int t, int w, int l, int lm, int quad,
        unsigned (&pk)[40]) {
    // W chunk 0 -> buf[1] (covered by first staging barrier)
    {
        const u16x8* src = (const u16x8*)Wl;
        u16x8* dst = (u16x8*)buf[1];
        dst[t] = src[t];
        dst[t + 512] = src[t + 512];
        dst[t + 1024] = src[t + 1024];
        dst[t + 1536] = src[t + 1536];
    }
    // stage x in two K-halves through buf[0]; build B-frags
    short8 bfrag[8];
    const int crow = t >> 5, f4 = t & 31;
#pragma unroll
    for (int kc = 0; kc < 2; ++kc) {
        float4 fr[8];
#pragma unroll
        for (int p = 0; p < 8; ++p) {
            int c = kc * 128 + p * 16 + crow;
            fr[p] = *(const float4*)(x + ((size_t)b * CIN + c) * II + i0 + 4 * f4);
        }
#pragma unroll
        for (int p = 0; p < 8; ++p) {
            int cl = p * 16 + crow;
            u16x4 u;
            u[0] = f2b(fr[p].x); u[1] = f2b(fr[p].y); u[2] = f2b(fr[p].z); u[3] = f2b(fr[p].w);
            *(u16x4*)&buf[0][cl * 132 + 4 * f4] = u;
        }
        __syncthreads();
#pragma unroll
        for (int k2 = 0; k2 < 4; ++k2) {
            short8 f;
#pragma unroll
            for (int j = 0; j < 8; ++j)
                f[j] = (short)buf[0][(k2 * 32 + quad * 8 + j) * 132 + w * 16 + lm];
            bfrag[kc * 4 + k2] = f;
        }
        __syncthreads();
    }
    // o-chunk loop (full unroll -> pk indices static)
#pragma unroll
    for (int oc = 0; oc < 5; ++oc) {
        if (oc < 4) {
            const u16x8* src = (const u16x8*)Wl + (size_t)(oc + 1) * 2048;
            u16x8* dst = (u16x8*)buf[oc & 1];
            dst[t] = src[t];
            dst[t + 512] = src[t + 512];
            dst[t + 1024] = src[t + 1024];
            dst[t + 1536] = src[t + 1536];
        }
        const unsigned short* ab = buf[(oc + 1) & 1];
        floatx4 acc[4] = {};
#pragma unroll
        for (int ks = 0; ks < 8; ++ks)
#pragma unroll
            for (int mtl = 0; mtl < 4; ++mtl) {
                short8 af = *(const short8*)(ab + (size_t)(((ks * 4 + mtl) * 4 + quad) * 16 + lm) * 8);
                acc[mtl] = __builtin_amdgcn_mfma_f32_16x16x32_bf16(af, bfrag[ks], acc[mtl], 0, 0, 0);
            }
        float av[16];
#pragma unroll
        for (int mtl = 0; mtl < 4; ++mtl) {
            int ob = oc * 64 + mtl * 16 + quad * 4;
#pragma unroll
            for (int r = 0; r < 4; ++r) av[mtl * 4 + r] = acc[mtl][r] + Wb_lds[ob + r];
            pk[oc * 8 + mtl * 2 + 0] =
                (unsigned)f2b(av[mtl * 4 + 0]) | ((unsigned)f2b(av[mtl * 4 + 1]) << 16);
            pk[oc * 8 + mtl * 2 + 1] =
                (unsigned)f2b(av[mtl * 4 + 2]) | ((unsigned)f2b(av[mtl * 4 + 3]) << 16);
        }
        // s1 partial: sum biased f32 pred over this wave's 16 i -> LDS atomic
        float q = butterfly16(av, l);
        atomicAdd(&sacc[oc * 64 + (lm >> 2) * 16 + quad * 4 + (lm & 3)], q);
        __syncthreads();
    }
}

// one routing pass over both sub-tiles: reduce 4 partial slices -> s ->
// squash v -> per-i delta (quad shuffles) -> b update -> thread-local softmax
// -> merged c*pred partial (lm butterfly + LDS atomics) -> per-block partial.
__device__ __forceinline__ void route_pass2(
        const float* __restrict__ srcpart, float scale, bool first,
        const unsigned (&pkA)[40], const unsigned (&pkB)[40],
        float (&bA)[JJ], float (&bB)[JJ], float* __restrict__ dstpart,
        float* sacc, float* v_lds, float* cf,
        int ic, int b, int t, int l, int lm, int quad) {
    if (t < OO) {
        float s = 0.f;
#pragma unroll
        for (int sl = 0; sl < 4; ++sl) s += srcpart[((size_t)sl * BS + b) * OO + t];
        sacc[t] = scale * s;
    }
    __syncthreads();
    if (t < JJ) {
        float n2 = 0.f;
#pragma unroll
        for (int d = 0; d < DD; ++d) { float v = sacc[t * DD + d]; n2 += v * v; }
        cf[t] = sqrtf(n2) / (1.0f + n2);
    }
    __syncthreads();
    if (t < OO) { v_lds[t] = sacc[t] * cf[t >> 5]; sacc[t] = 0.f; }
    __syncthreads();

    // delta[i][j] = sum_d v[j][d]*pred[i][j][d]; thread holds 8 d per j (quad)
    float djA[JJ], djB[JJ];
#pragma unroll
    for (int j = 0; j < JJ; ++j) { djA[j] = 0.f; djB[j] = 0.f; }
#pragma unroll
    for (int m = 0; m < 20; ++m) {       // o = m*16 + quad*4 + r
        float4 vv = *(const float4*)&v_lds[m * 16 + quad * 4];
        unsigned a0 = pkA[2 * m], a1 = pkA[2 * m + 1];
        djA[m >> 1] += b2f((unsigned short)(a0 & 0xffffu)) * vv.x
                     + b2f((unsigned short)(a0 >> 16)) * vv.y
                     + b2f((unsigned short)(a1 & 0xffffu)) * vv.z
                     + b2f((unsigned short)(a1 >> 16)) * vv.w;
        unsigned b0 = pkB[2 * m], b1 = pkB[2 * m + 1];
        djB[m >> 1] += b2f((unsigned short)(b0 & 0xffffu)) * vv.x
                     + b2f((unsigned short)(b0 >> 16)) * vv.y
                     + b2f((unsigned short)(b1 & 0xffffu)) * vv.z
                     + b2f((unsigned short)(b1 >> 16)) * vv.w;
    }
#pragma unroll
    for (int j = 0; j < JJ; ++j) {       // complete dot over quads
        float dA = djA[j];
        dA += __shfl_xor(dA, 16);
        dA += __shfl_xor(dA, 32);
        bA[j] = first ? dA : (bA[j] + dA);
        float dB = djB[j];
        dB += __shfl_xor(dB, 16);
        dB += __shfl_xor(dB, 32);
        bB[j] = first ? dB : (bB[j] + dB);
    }
    // thread-local softmax over j for each owned i
    float mA = bA[0], mB = bB[0];
#pragma unroll
    for (int j = 1; j < JJ; ++j) { mA = fmaxf(mA, bA[j]); mB = fmaxf(mB, bB[j]); }
    float cjA[JJ], cjB[JJ], ZA = 0.f, ZB = 0.f;
#pragma unroll
    for (int j = 0; j < JJ; ++j) {
        cjA[j] = __expf(bA[j] - mA); ZA += cjA[j];
        cjB[j] = __expf(bB[j] - mB); ZB += cjB[j];
    }
    float invA = 1.0f / ZA, invB = 1.0f / ZB;
    // psum[j][d] partial over block's 256 i: merge A+B, 5 groups of 16
#pragma unroll
    for (int g = 0; g < 5; ++g) {
        float v16[16];
#pragma unroll
        for (int mm = 0; mm < 4; ++mm) {
            int m = 4 * g + mm;
            unsigned a0 = pkA[2 * m], a1 = pkA[2 * m + 1];
            unsigned b0 = pkB[2 * m], b1 = pkB[2 * m + 1];
            float cA = cjA[m >> 1] * invA, cB = cjB[m >> 1] * invB;
            v16[4 * mm + 0] = cA * b2f((unsigned short)(a0 & 0xffffu))
                            + cB * b2f((unsigned short)(b0 & 0xffffu));
            v16[4 * mm + 1] = cA * b2f((unsigned short)(a0 >> 16))
                            + cB * b2f((unsigned short)(b0 >> 16));
            v16[4 * mm + 2] = cA * b2f((unsigned short)(a1 & 0xffffu))
                            + cB * b2f((unsigned short)(b1 & 0xffffu));
            v16[4 * mm + 3] = cA * b2f((unsigned short)(a1 >> 16))
                            + cB * b2f((unsigned short)(b1 >> 16));
        }
        float q = butterfly16(v16, l);
        atomicAdd(&sacc[g * 64 + (lm >> 2) * 16 + quad * 4 + (lm & 3)], q);
    }
    __syncthreads();
    if (t < OO) dstpart[((size_t)ic * BS + b) * OO + t] = sacc[t];
}

__global__ __launch_bounds__(512, 2) void k_mega(
        const float* __restrict__ x, const unsigned short* __restrict__ Wl,
        const float* __restrict__ Wb, float* __restrict__ s1part,
        float* __restrict__ psum1, float* __restrict__ psum2,
        float* __restrict__ out) {
    __shared__ unsigned short buf[2][16896];        // 67,584 B
    __shared__ float Wb_lds[OO];
    __shared__ float sacc[OO];
    __shared__ __align__(16) float v_lds[OO];
    __shared__ float cf[16];

    cg::grid_group gg = cg::this_grid();

    const int ic = blockIdx.x, b = blockIdx.y;      // ic in [0,4)
    const int t = threadIdx.x, w = t >> 6, l = t & 63;
    const int lm = l & 15, quad = l >> 4;

    if (t < OO) { Wb_lds[t] = Wb[t]; sacc[t] = 0.f; }

    // two 128-i sub-tiles; pred packed into registers
    unsigned pkA[40], pkB[40];
    gemm_subtile(x, Wl, buf, Wb_lds, sacc, b, ic * 256, t, w, l, lm, quad, pkA);
    gemm_subtile(x, Wl, buf, Wb_lds, sacc, b, ic * 256 + 128, t, w, l, lm, quad, pkB);

    // per-block s1 partial (sum over 256 i, bias included)
    if (t < OO) s1part[((size_t)ic * BS + b) * OO + t] = sacc[t];
    __threadfence();
    gg.sync();

    // routing pass 1 (uniform c handled by 0.1*s1)
    float bA[JJ], bB[JJ];
    route_pass2(s1part, 0.1f, true, pkA, pkB, bA, bB, psum1,
                sacc, v_lds, cf, ic, b, t, l, lm, quad);
    __threadfence();
    gg.sync();

    // routing pass 2
    route_pass2(psum1, 1.0f, false, pkA, pkB, bA, bB, psum2,
                sacc, v_lds, cf, ic, b, t, l, lm, quad);
    __threadfence();
    gg.sync();

    // final squash + output (one block per batch)
    if (ic == 0) {
        if (t < OO) {
            float s = 0.f;
#pragma unroll
            for (int sl = 0; sl < 4; ++sl) s += psum2[((size_t)sl * BS + b) * OO + t];
            sacc[t] = s;
        }
        __syncthreads();
        if (t < JJ) {
            float n2 = 0.f;
#pragma unroll
            for (int d = 0; d < DD; ++d) { float v = sacc[t * DD + d]; n2 += v * v; }
            cf[t] = sqrtf(n2) / (1.0f + n2);
        }
        __syncthreads();
        if (t < OO) out[b * OO + t] = sacc[t] * cf[t >> 5];
    }
}

// ============================================================================
//            FALLBACK: verified 6-kernel pipeline (unchanged)
// ============================================================================

__global__ __launch_bounds__(512) void k_gemm8(const float* __restrict__ x,
                                               const unsigned short* __restrict__ Wl,
                                               const float* __restrict__ Wb,
                                               unsigned short* __restrict__ pred,
                                               float* __restrict__ psumC) {
    __shared__ unsigned short buf[2][16896];
    __shared__ float Wb_lds[OO];

    const int ic = blockIdx.x, b = blockIdx.y;
    const int t = threadIdx.x, w = t >> 6, l = t & 63;
    const int lm = l & 15, quad = l >> 4;
    const int i0 = ic * 128;

    if (t < OO) Wb_lds[t] = Wb[t];

    {
        const u16x8* src = (const u16x8*)Wl;
        u16x8* dst = (u16x8*)buf[1];
        dst[t] = src[t];
        dst[t + 512] = src[t + 512];
        dst[t + 1024] = src[t + 1024];
        dst[t + 1536] = src[t + 1536];
    }

    short8 bfrag[8];
    float csum[2];
    const int crow = t >> 5, f4 = t & 31;
    const int cs_c = t >> 2, cs_seg = t & 3;
#pragma unroll
    for (int kc = 0; kc < 2; ++kc) {
        float4 fr[8];
#pragma unroll
        for (int p = 0; p < 8; ++p) {
            int c = kc * 128 + p * 16 + crow;
            fr[p] = *(const float4*)(x + ((size_t)b * CIN + c) * II + i0 + 4 * f4);
        }
#pragma unroll
        for (int p = 0; p < 8; ++p) {
            int cl = p * 16 + crow;
            u16x4 u;
            u[0] = f2b(fr[p].x); u[1] = f2b(fr[p].y); u[2] = f2b(fr[p].z); u[3] = f2b(fr[p].w);
            *(u16x4*)&buf[0][cl * 132 + 4 * f4] = u;
        }
        __syncthreads();
#pragma unroll
        for (int k2 = 0; k2 < 4; ++k2) {
            short8 f;
#pragma unroll
            for (int j = 0; j < 8; ++j)
                f[j] = (short)buf[0][(k2 * 32 + quad * 8 + j) * 132 + w * 16 + lm];
            bfrag[kc * 4 + k2] = f;
        }
        {
            float cs = 0.f;
#pragma unroll
            for (int q = 0; q < 8; ++q) {
                u16x4 u = *(const u16x4*)&buf[0][cs_c * 132 + cs_seg * 32 + q * 4];
                cs += b2f(u[0]) + b2f(u[1]) + b2f(u[2]) + b2f(u[3]);
            }
            cs += __shfl_xor(cs, 1);
            cs += __shfl_xor(cs, 2);
            csum[kc] = cs;
        }
        __syncthreads();
    }
    if (cs_seg == 0) {
        size_t cbase = ((size_t)ic * BS + b) * CIN;
        psumC[cbase + cs_c] = csum[0];
        psumC[cbase + 128 + cs_c] = csum[1];
    }

    const size_t predrow = ((size_t)b * II + i0 + w * 16 + lm) * OO;
#pragma unroll 1
    for (int oc = 0; oc < 5; ++oc) {
        if (oc < 4) {
            const u16x8* src = (const u16x8*)Wl + (size_t)(oc + 1) * 2048;
            u16x8* dst = (u16x8*)buf[oc & 1];
            dst[t] = src[t];
            dst[t + 512] = src[t + 512];
            dst[t + 1024] = src[t + 1024];
            dst[t + 1536] = src[t + 1536];
        }
        const unsigned short* ab = buf[(oc + 1) & 1];
        floatx4 acc[4] = {};
#pragma unroll
        for (int ks = 0; ks < 8; ++ks)
#pragma unroll
            for (int mtl = 0; mtl < 4; ++mtl) {
                short8 af = *(const short8*)(ab + (size_t)(((ks * 4 + mtl) * 4 + quad) * 16 + lm) * 8);
                acc[mtl] = __builtin_amdgcn_mfma_f32_16x16x32_bf16(af, bfrag[ks], acc[mtl], 0, 0, 0);
            }
#pragma unroll
        for (int mtl = 0; mtl < 4; ++mtl) {
            int ob = oc * 64 + mtl * 16 + quad * 4;
            u16x4 sv;
#pragma unroll
            for (int r = 0; r < 4; ++r) sv[r] = f2b(acc[mtl][r] + Wb_lds[ob + r]);
            *(u16x4*)(pred + predrow + ob) = sv;
        }
        __syncthreads();
    }
}

__global__ __launch_bounds__(320) void k_gemv(const float* __restrict__ psumC,
                                              const float* __restrict__ W,
                                              const float* __restrict__ Wb,
                                              float* __restrict__ s1) {
    __shared__ float y_lds[CIN];
    const int b = blockIdx.x, t = threadIdx.x;
    if (t < CIN) {
        float s = 0.f;
#pragma unroll
        for (int sl = 0; sl < 8; ++sl) s += psumC[((size_t)sl * BS + b) * CIN + t];
        y_lds[t] = s;
    }
    __syncthreads();
    const float* wr = W + (size_t)t * CIN;
    float acc = 0.f;
#pragma unroll 4
    for (int c = 0; c < CIN; c += 4) {
        float4 wv = *(const float4*)(wr + c);
        acc += wv.x * y_lds[c] + wv.y * y_lds[c + 1] + wv.z * y_lds[c + 2] + wv.w * y_lds[c + 3];
    }
    s1[(size_t)b * OO + t] = 0.1f * (acc + 1024.0f * Wb[t]);
}

__global__ __launch_bounds__(640) void k_route1(const float* __restrict__ s1,
                                                const unsigned short* __restrict__ pred,
                                                float* __restrict__ blogG,
                                                float* __restrict__ psum1) {
    __shared__ float s_lds[OO];
    __shared__ float v_lds[OO];
    __shared__ float cf[JJ];
    __shared__ float dbuf[JJ][128];

    const int ic = blockIdx.x, b = blockIdx.y;
    const int t = threadIdx.x, w = t >> 6, l = t & 63;

    u16x8 va[4], vb[4];
    {
        const unsigned short* p0 = pred + ((size_t)b * II + ic * 128 + 2 * l) * OO + w * DD;
#pragma unroll
        for (int q = 0; q < 4; ++q) {
            va[q] = *(const u16x8*)(p0 + q * 8);
            vb[q] = *(const u16x8*)(p0 + OO + q * 8);
        }
    }

    if (t < OO) s_lds[t] = s1[(size_t)b * OO + t];
    __syncthreads();
    if (t < JJ) {
        float n2 = 0.f;
#pragma unroll
        for (int d = 0; d < DD; ++d) { float v = s_lds[t * DD + d]; n2 += v * v; }
        cf[t] = sqrtf(n2) / (1.0f + n2);
    }
    __syncthreads();
    if (t < OO) v_lds[t] = s_lds[t] * cf[t >> 5];
    __syncthreads();

    float d0 = 0.f, d1 = 0.f;
#pragma unroll
    for (int q = 0; q < 4; ++q)
#pragma unroll
        for (int e = 0; e < 8; ++e) {
            float vv = v_lds[w * DD + q * 8 + e];
            d0 += vv * b2f(va[q][e]);
            d1 += vv * b2f(vb[q][e]);
        }
    *(float2*)(blogG + ((size_t)b * JJ + w) * II + ic * 128 + 2 * l) = make_float2(d0, d1);
    dbuf[w][2 * l] = d0; dbuf[w][2 * l + 1] = d1;
    __syncthreads();

    if (t < 128) {
        float lg[JJ];
#pragma unroll
        for (int j = 0; j < JJ; ++j) lg[j] = dbuf[j][t];
        float m = lg[0];
#pragma unroll
        for (int j = 1; j < JJ; ++j) m = fmaxf(m, lg[j]);
        float Z = 0.f, c[JJ];
#pragma unroll
        for (int j = 0; j < JJ; ++j) { c[j] = __expf(lg[j] - m); Z += c[j]; }
        float inv = 1.0f / Z;
#pragma unroll
        for (int j = 0; j < JJ; ++j) dbuf[j][t] = c[j] * inv;
    }
    __syncthreads();

    float c0 = dbuf[w][2 * l], c1 = dbuf[w][2 * l + 1];
    float p[DD];
#pragma unroll
    for (int q = 0; q < 4; ++q)
#pragma unroll
        for (int e = 0; e < 8; ++e)
            p[q * 8 + e] = c0 * b2f(va[q][e]) + c1 * b2f(vb[q][e]);
    float s = butterfly32(p, l);
    if (l < 32) psum1[((size_t)ic * BS + b) * OO + w * DD + l] = s;
}

__global__ __launch_bounds__(640) void k_route2(const float* __restrict__ psum1,
                                                const unsigned short* __restrict__ pred,
                                                const float* __restrict__ blogG,
                                                float* __restrict__ psum2) {
    __shared__ float s_lds[OO];
    __shared__ float v_lds[OO];
    __shared__ float cf[JJ];
    __shared__ float dbuf[JJ][128];

    const int ic = blockIdx.x, b = blockIdx.y;
    const int t = threadIdx.x, w = t >> 6, l = t & 63;

    u16x8 va[4], vb[4];
    {
        const unsigned short* p0 = pred + ((size_t)b * II + ic * 128 + 2 * l) * OO + w * DD;
#pragma unroll
        for (int q = 0; q < 4; ++q) {
            va[q] = *(const u16x8*)(p0 + q * 8);
            vb[q] = *(const u16x8*)(p0 + OO + q * 8);
        }
    }

    if (t < OO) {
        float s = 0.f;
#pragma unroll
        for (int sl = 0; sl < 8; ++sl) s += psum1[((size_t)sl * BS + b) * OO + t];
        s_lds[t] = s;
    }
    __syncthreads();
    if (t < JJ) {
        float n2 = 0.f;
#pragma unroll
        for (int d = 0; d < DD; ++d) { float v = s_lds[t * DD + d]; n2 += v * v; }
        cf[t] = sqrtf(n2) / (1.0f + n2);
    }
    __syncthreads();
    if (t < OO) v_lds[t] = s_lds[t] * cf[t >> 5];
    __syncthreads();

    float d0 = 0.f, d1 = 0.f;
#pragma unroll
    for (int q = 0; q < 4; ++q)
#pragma unroll
        for (int e = 0; e < 8; ++e) {
            float vv = v_lds[w * DD + q * 8 + e];
            d0 += vv * b2f(va[q][e]);
            d1 += vv * b2f(vb[q][e]);
        }
    float2 bl = *(const float2*)(blogG + ((size_t)b * JJ + w) * II + ic * 128 + 2 * l);
    dbuf[w][2 * l] = bl.x + d0; dbuf[w][2 * l + 1] = bl.y + d1;
    __syncthreads();

    if (t < 128) {
        float lg[JJ];
#pragma unroll
        for (int j = 0; j < JJ; ++j) lg[j] = dbuf[j][t];
        float m = lg[0];
#pragma unroll
        for (int j = 1; j < JJ; ++j) m = fmaxf(m, lg[j]);
        float Z = 0.f, c[JJ];
#pragma unroll
        for (int j = 0; j < JJ; ++j) { c[j] = __expf(lg[j] - m); Z += c[j]; }
        float inv = 1.0f / Z;
#pragma unroll
        for (int j = 0; j < JJ; ++j) dbuf[j][t] = c[j] * inv;
    }
    __syncthreads();

    float c0 = dbuf[w][2 * l], c1 = dbuf[w][2 * l + 1];
    float p[DD];
#pragma unroll
    for (int q = 0; q < 4; ++q)
#pragma unroll
        for (int e = 0; e < 8; ++e)
            p[q * 8 + e] = c0 * b2f(va[q][e]) + c1 * b2f(vb[q][e]);
    float s = butterfly32(p, l);
    if (l < 32) psum2[((size_t)ic * BS + b) * OO + w * DD + l] = s;
}

__global__ __launch_bounds__(320) void k_final2(const float* __restrict__ psum2,
                                                float* __restrict__ out) {
    __shared__ float s_lds[OO];
    __shared__ float cf[JJ];
    int b = blockIdx.x, t = threadIdx.x;
    float s = 0.f;
#pragma unroll
    for (int sl = 0; sl < 8; ++sl) s += psum2[((size_t)sl * BS + b) * OO + t];
    s_lds[t] = s;
    __syncthreads();
    if (t < JJ) {
        float n2 = 0.f;
#pragma unroll
        for (int d = 0; d < DD; ++d) { float v = s_lds[t * DD + d]; n2 += v * v; }
        cf[t] = sqrtf(n2) / (1.0f + n2);
    }
    __syncthreads();
    out[b * OO + t] = s_lds[t] * cf[t >> 5];
}

extern "C" void kernel_launch(void* const* d_in, const int* in_sizes, int n_in,
                              void* d_out, int out_size, void* d_ws, size_t ws_size,
                              hipStream_t stream) {
    const float* x  = (const float*)d_in[0];  // [64][256][1024] f32
    const float* W  = (const float*)d_in[1];  // [320][256] f32
    const float* Wb = (const float*)d_in[2];  // [320] f32

    char* ws = (char*)d_ws;
    unsigned short* pred = (unsigned short*)ws;              // 41,943,040 B  (fallback only)
    unsigned short* Wl   = (unsigned short*)(ws + 41943040); // 163,840 B
    float* psumC = (float*)(ws + 42106880);                  // 524,288 B (fallback only)
    float* s1    = (float*)(ws + 42631168);                  // 81,920 B  (fallback only)
    float* psum1 = (float*)(ws + 42713088);                  // 655,360 B
    float* psum2 = (float*)(ws + 43368448);                  // 655,360 B
    float* blogG = (float*)(ws + 44023808);                  // 2,621,440 B (fallback only)
    float* s1part = (float*)(ws + 46645248);                 // 655,360 B (mega only)

    k_prepW<<<40, 256, 0, stream>>>(W, Wl);

    // primary: single cooperative fused kernel, 256 blocks (1/CU), 256-reg budget
    {
        const float* a0 = x;
        const unsigned short* a1 = Wl;
        const float* a2 = Wb;
        float* a3 = s1part;
        float* a4 = psum1;
        float* a5 = psum2;
        float* a6 = (float*)d_out;
        void* kargs[] = {&a0, &a1, &a2, &a3, &a4, &a5, &a6};
        hipError_t e = hipLaunchCooperativeKernel(k_mega, dim3(4, BS), dim3(512, 1, 1),
                                                  kargs, 0, stream);
        if (e == hipSuccess) return;
    }

    // fallback: verified 6-kernel pipeline
    k_gemm8<<<dim3(8, BS), 512, 0, stream>>>(x, Wl, Wb, pred, psumC);
    k_gemv<<<BS, 320, 0, stream>>>(psumC, W, Wb, s1);
    k_route1<<<dim3(8, BS), 640, 0, stream>>>(s1, pred, blogG, psum1);
    k_route2<<<dim3(8, BS), 640, 0, stream>>>(psum1, pred, blogG, psum2);
    k_final2<<<BS, 320, 0, stream>>>(psum2, (float*)d_out);
}